// Round 7
// baseline (377.429 us; speedup 1.0000x reference)
//
#include <hip/hip_runtime.h>
#include <stdint.h>

#define D_DIM 2048
#define K_DIM 64
#define T_DIM 2048
#define BT_DIM 16384   // B*T = 8*2048

typedef __attribute__((address_space(3))) uint32_t lds_u32;
typedef const __attribute__((address_space(1))) uint32_t glob_u32;

// ---------------------------------------------------------------------------
// Kernel A: softmax over k of w[d,:], stored PACKED for the gemm:
//   pC[(d>>2)*256 + k*4 + (d&3)] = softmax(w[d,:])[k]
// ---------------------------------------------------------------------------
__global__ __launch_bounds__(256) void softmax_k(const float* __restrict__ w,
                                                 float* __restrict__ pC) {
    const int lane = threadIdx.x & 63;
    const int d = blockIdx.x * 4 + (threadIdx.x >> 6);
    float v = w[d * K_DIM + lane];
    float m = v;
#pragma unroll
    for (int off = 32; off > 0; off >>= 1) m = fmaxf(m, __shfl_xor(m, off, 64));
    float e = expf(v - m);
    float s = e;
#pragma unroll
    for (int off = 32; off > 0; off >>= 1) s += __shfl_xor(s, off, 64);
    pC[(d >> 2) * 256 + lane * 4 + (d & 3)] = e / s;
}

// ---------------------------------------------------------------------------
// Kernel B: per-column min/max of w -> nT[k,d] = (w[d,k]-mn)/(mx-mn).
// ---------------------------------------------------------------------------
__global__ __launch_bounds__(256) void norm_k(const float* __restrict__ w,
                                              float* __restrict__ nT) {
    const int k = blockIdx.x;
    const int lane = threadIdx.x & 63;
    const int wave = threadIdx.x >> 6;
    float mn = 1e30f, mx = -1e30f;
    for (int d = threadIdx.x; d < D_DIM; d += 256) {
        float v = w[d * K_DIM + k];
        mn = fminf(mn, v);
        mx = fmaxf(mx, v);
    }
#pragma unroll
    for (int off = 32; off > 0; off >>= 1) {
        mn = fminf(mn, __shfl_xor(mn, off, 64));
        mx = fmaxf(mx, __shfl_xor(mx, off, 64));
    }
    __shared__ float red[8];
    if (lane == 0) { red[wave] = mn; red[4 + wave] = mx; }
    __syncthreads();
    mn = fminf(fminf(red[0], red[1]), fminf(red[2], red[3]));
    mx = fmaxf(fmaxf(red[4], red[5]), fmaxf(red[6], red[7]));
    const float inv = 1.0f / (mx - mn);
    for (int d = threadIdx.x; d < D_DIM; d += 256) {
        nT[k * D_DIM + d] = (w[d * K_DIM + k] - mn) * inv;
    }
}

// ---------------------------------------------------------------------------
// Kernel C (FUSED): scores = X @ P -> per-row (argmax,sign) -> output rows.
// v7:
//  - 16 rows/block, grid 1024 = 4 blocks/CU = 4 waves/SIMD (2x TLP vs v6;
//    v6's grid of 512 capped occupancy at 2 waves/SIMD, VALUBusy 40%).
//  - acc[4][4]/lane; per-wave dbuf LDS tile [16][64] (32 KB/block);
//    counted s_waitcnt vmcnt(4) (= the 4 just-issued stage loads).
//  - Swizzle re-derived for 16 rows: rg = row>>2, stage swz = j,
//    read slot = c ^ rg (4 rgs -> 4 distinct 16B slots, conflict-free).
//  - FUSION via shifted output window: this block computes stats for rows
//    r0..r0+15 (in LDS only - no global stats) and outputs rows r0+1..r0+16,
//    each needing stats[row-1] which is in-block. Row 0 (t==0, W=0) is a
//    copy, written by block 0. No cross-block dependency.
//  - Per-(row,k) FMA chaining, cross-wave reduce and argmax identical to the
//    verified v4/v6 -> stats bit-identical -> output bit-identical.
// ---------------------------------------------------------------------------
__global__ __launch_bounds__(256, 4) void gemm_out_k(const float* __restrict__ x,
                                                     const float* __restrict__ pC,
                                                     const float* __restrict__ nT,
                                                     float* __restrict__ out) {
    const int lane = threadIdx.x & 63;
    const int wave = threadIdx.x >> 6;
    const int r0 = blockIdx.x * 16;
    const int dw0 = wave * (D_DIM / 4);            // this wave's d-quarter
    const int rg = lane >> 4;                      // 0..3: rows rg*4..rg*4+3
    const int kg = lane & 15;                      // k = kg*4 + kk

    __shared__ float xs_all[4][2][16 * 64];        // 32 KB: per-wave double buffer
    __shared__ int sstat[16];
    float* cur = &xs_all[wave][0][0];
    float* nxt = &xs_all[wave][1][0];

    float acc[4][4];
#pragma unroll
    for (int rr = 0; rr < 4; ++rr)
#pragma unroll
        for (int kk = 0; kk < 4; ++kk) acc[rr][kk] = 0.0f;

    const float* __restrict__ xg = x + (size_t)r0 * D_DIM + dw0;   // wave x panel
    const float* __restrict__ pgBase = pC + (size_t)(wave * 128) * 256 + kg * 16;

    const int srow = lane >> 4;                    // staging row within group of 4

    // ---- prologue: stage tile 0 into cur (4 x 1KB; rows j*4+srow, swz=j)
#pragma unroll
    for (int j = 0; j < 4; ++j) {
        const float* src = xg + (size_t)(j * 4 + srow) * D_DIM + ((kg ^ j) << 2);
        __builtin_amdgcn_global_load_lds((glob_u32*)src, (lds_u32*)(cur + j * 256),
                                         16, 0, 0);
    }

#pragma unroll 1
    for (int it = 0; it < 8; ++it) {
        // ---- issue staging of tile it+1 into nxt, then wait ONLY for tile it
        if (it < 7) {
#pragma unroll
            for (int j = 0; j < 4; ++j) {
                const float* src = xg + (size_t)(j * 4 + srow) * D_DIM
                                   + (it + 1) * 64 + ((kg ^ j) << 2);
                __builtin_amdgcn_global_load_lds((glob_u32*)src,
                                                 (lds_u32*)(nxt + j * 256),
                                                 16, 0, 0);
            }
            asm volatile("s_waitcnt vmcnt(4)" ::: "memory");
        } else {
            asm volatile("s_waitcnt vmcnt(0)" ::: "memory");
        }

        // ---- compute: 16 sub-chunks of 4 d
#pragma unroll
        for (int c = 0; c < 16; ++c) {
            const float* pcc = pgBase + (size_t)(it * 16 + c) * 256;
            float4 pv[4];
#pragma unroll
            for (int kk = 0; kk < 4; ++kk)
                pv[kk] = *(const float4*)(pcc + kk * 4);
#pragma unroll
            for (int rr = 0; rr < 4; ++rr) {
                const int row = rg * 4 + rr;
                const float4 xv = *(const float4*)(cur + row * 64 + ((c ^ rg) << 2));
#pragma unroll
                for (int kk = 0; kk < 4; ++kk) {
                    float a = acc[rr][kk];
                    a = fmaf(xv.x, pv[kk].x, a);
                    a = fmaf(xv.y, pv[kk].y, a);
                    a = fmaf(xv.z, pv[kk].z, a);
                    a = fmaf(xv.w, pv[kk].w, a);
                    acc[rr][kk] = a;
                }
            }
        }
        float* t = cur; cur = nxt; nxt = t;
    }

    // ---- cross-wave reduction + 64-lane argmax -> sstat (LDS only) --------
    __syncthreads();                               // all waves done with xs
    float (*red)[16][64] = reinterpret_cast<float (*)[16][64]>(&xs_all[0][0][0]);
#pragma unroll
    for (int rr = 0; rr < 4; ++rr)
#pragma unroll
        for (int kk = 0; kk < 4; ++kk)
            red[wave][rg * 4 + rr][kg * 4 + kk] = acc[rr][kk];
    __syncthreads();

#pragma unroll
    for (int rr = 0; rr < 4; ++rr) {
        const int r = wave * 4 + rr;
        float v = red[0][r][lane] + red[1][r][lane] + red[2][r][lane] + red[3][r][lane];
        int idx = lane;
#pragma unroll
        for (int off = 32; off > 0; off >>= 1) {
            const float ov = __shfl_xor(v, off, 64);
            const int oi = __shfl_xor(idx, off, 64);
            if (ov > v || (ov == v && oi < idx)) { v = ov; idx = oi; }
        }
        if (lane == 0) sstat[r] = idx | ((v < 0.0f) ? (1 << 8) : 0);
    }
    __syncthreads();

    // ---- fused output: rows r0+1 .. r0+16 (stats[row-1] = sstat[rr]) ------
    const int tid = threadIdx.x;
    if (blockIdx.x == 0) {                         // row 0: W = 0 -> copy
        const float4* x4 = (const float4*)x;
        float4* o4 = (float4*)out;
#pragma unroll
        for (int i2 = 0; i2 < 2; ++i2) o4[tid + i2 * 256] = x4[tid + i2 * 256];
    }
#pragma unroll 1
    for (int rr = 0; rr < 16; ++rr) {
        const int row = r0 + 1 + rr;
        if (row >= BT_DIM) break;
        const int t = row & (T_DIM - 1);
        const float4* x4 = (const float4*)(x + (size_t)row * D_DIM);
        float4* o4 = (float4*)(out + (size_t)row * D_DIM);
        if (t == 0) {                              // W = 0 -> copy
#pragma unroll
            for (int i2 = 0; i2 < 2; ++i2) o4[tid + i2 * 256] = x4[tid + i2 * 256];
            continue;
        }
        const int s = sstat[rr];
        const int ind = s & 0xff;
        const bool neg = (s >> 8) & 1;
        const float4* n4 = (const float4*)(nT + (size_t)ind * D_DIM);
#pragma unroll
        for (int i2 = 0; i2 < 2; ++i2) {
            const int i = tid + i2 * 256;
            const float4 xv = x4[i];
            const float4 nv = n4[i];
            float4 r;
            const float w0 = neg ? 1.0f - nv.x : nv.x;
            const float w1 = neg ? 1.0f - nv.y : nv.y;
            const float w2 = neg ? 1.0f - nv.z : nv.z;
            const float w3 = neg ? 1.0f - nv.w : nv.w;
            r.x = fmaf(xv.x, w0, xv.x);
            r.y = fmaf(xv.y, w1, xv.y);
            r.z = fmaf(xv.z, w2, xv.z);
            r.w = fmaf(xv.w, w3, xv.w);
            o4[i] = r;
        }
    }
}

extern "C" void kernel_launch(void* const* d_in, const int* in_sizes, int n_in,
                              void* d_out, int out_size, void* d_ws, size_t ws_size,
                              hipStream_t stream) {
    const float* x = (const float*)d_in[0];   // [B,T,D] fp32
    const float* w = (const float*)d_in[1];   // [D,K] fp32
    float* out = (float*)d_out;

    float* pC = (float*)d_ws;                 // [D/4][K][4] packed softmax, 512 KB
    float* nT = pC + (size_t)K_DIM * D_DIM;   // [K,D]  512 KB

    softmax_k<<<D_DIM / 4, 256, 0, stream>>>(w, pC);
    norm_k<<<K_DIM, 256, 0, stream>>>(w, nT);
    gemm_out_k<<<BT_DIM / 16, 256, 0, stream>>>(x, pC, nT, out);
}